// Round 5
// baseline (26183.472 us; speedup 1.0000x reference)
//
#include <hip/hip_runtime.h>

typedef __attribute__((ext_vector_type(8))) short bhalf8;
typedef __attribute__((ext_vector_type(4))) float floatx4;

#define NSLOTS 502
#define NWG 96
#define BLOCK 768   // 12 waves: (side 2) x (gate 3) x (col-half 2)

#define AS1 __attribute__((address_space(1)))
#define AS3 __attribute__((address_space(3)))
// global->LDS direct, 16B/lane. aux=17 = sc0|sc1 (coherent, MALL-served). aux=0 = cached.
#define GLL_COH(g, s)   __builtin_amdgcn_global_load_lds((const AS1 unsigned*)(g), (AS3 unsigned*)(s), 16, 0, 17)
#define GLL_PLAIN(g, s) __builtin_amdgcn_global_load_lds((const AS1 unsigned*)(g), (AS3 unsigned*)(s), 16, 0, 0)

__device__ __forceinline__ unsigned short f2b(float f) {
  unsigned u = __float_as_uint(f);
  return (unsigned short)((u + 0x7FFFu + ((u >> 16) & 1u)) >> 16);
}
__device__ __forceinline__ void cstore(unsigned long long* p, unsigned long long v) {
  __hip_atomic_store(p, v, __ATOMIC_RELAXED, __HIP_MEMORY_SCOPE_AGENT);
}
__device__ __forceinline__ int cloadi(const int* p) {
  return __hip_atomic_load(p, __ATOMIC_RELAXED, __HIP_MEMORY_SCOPE_AGENT);
}

__global__ void prep_w(const float* __restrict__ wih, const float* __restrict__ whh,
                       const float* __restrict__ wout,
                       unsigned short* __restrict__ wihb, unsigned short* __restrict__ whhb,
                       unsigned short* __restrict__ woutb) {
  size_t i0 = (size_t)blockIdx.x * blockDim.x + threadIdx.x;
  size_t stride = (size_t)gridDim.x * blockDim.x;
  for (size_t i = i0; i < 6291456u; i += stride) { wihb[i] = f2b(wih[i]); whhb[i] = f2b(whh[i]); }
  for (size_t i = i0; i < 163840u; i += stride) woutb[i] = f2b(wout[i]);
}

// res_output (B=64, H=1024, T=500) f32 -> xb (T, B, H) bf16
__global__ void prep_x(const float* __restrict__ x, unsigned short* __restrict__ xb) {
  __shared__ float tile[32][33];
  int b = blockIdx.z;
  int h0 = blockIdx.y * 32, t0 = blockIdx.x * 32;
  int tx = threadIdx.x, ty = threadIdx.y;
  #pragma unroll
  for (int i = 0; i < 32; i += 8) {
    int t = t0 + tx;
    if (t < 500) tile[ty + i][tx] = x[((size_t)b * 1024 + h0 + ty + i) * 500 + t];
  }
  __syncthreads();
  #pragma unroll
  for (int i = 0; i < 32; i += 8) {
    int t = t0 + ty + i;
    if (t < 500) xb[((size_t)t * 64 + b) * 1024 + h0 + tx] = f2b(tile[tx][ty + i]);
  }
}

// ws layout (bytes):
// 0       : flags (96 ints, monotonic "completed slots"), pad to 1024
// 1024    : h0b[3] x 131072   (triple-buffered h0, bf16 64x1024)
// 394240  : h1b[2] x 131072
// --- zero region ends at 656384 ---
// 656384  : Woutb (160*1024 bf16)           -> 984064
// 984064  : Wihb  (2*3072*1024 bf16)        -> 13566976
// 13566976: Whhb                             -> 26149888
// 26149888: Xb (500*64*1024 bf16)            -> 91685888

__launch_bounds__(BLOCK, 1)
__global__ void gru_main(const unsigned short* __restrict__ xb,
                         const unsigned short* __restrict__ wihb,
                         const unsigned short* __restrict__ whhb,
                         const unsigned short* __restrict__ woutb,
                         const float* __restrict__ bih, const float* __restrict__ bhh,
                         const float* __restrict__ bout,
                         char* __restrict__ wsb, float* __restrict__ out) {
  int* flg = (int*)wsb;
  char* h0b[3] = { wsb + 1024, wsb + 132096, wsb + 263168 };
  char* h1b[2] = { wsb + 394240, wsb + 525312 };

  const int wg = blockIdx.x;
  const int layer = (wg < 32) ? 0 : 1;
  const int idx1 = wg - 32;
  const int c    = (layer == 0) ? wg : (idx1 & 31);   // col-chunk: n in [c*32, c*32+32)
  const int half = (layer == 0) ? 0  : (idx1 >> 5);   // L1 batch-half: rows [half*32, +32)
  const int n0 = c * 32;
  const int tid = threadIdx.x;
  const int w = tid >> 6;          // wave 0..11
  const int l = tid & 63;
  const int l15 = l & 15, l4 = l >> 4;
  const int sd = w / 6;            // side 0=input, 1=recurrent
  const int g = (w % 6) >> 1;      // gate r,z,n
  const int u = w & 1;             // col half (16 cols)

  // LDS: L0: [0,128K) h0 plane (64 rows x 2048B, src-swizzled) + [128K,152K) x ring 3x8KB
  //      L1: [0,64K) h0 plane (32 rows) + [64K,128K) h1 plane (32 rows)
  //      Gs gate planes overlay [0,..) after compute.
  __shared__ __align__(16) char smem[155648];

  // ---- weights: VGPR-resident (anchored each slot, see loop top)
  const unsigned short* Wside = (sd == 0 ? wihb : whhb) + (size_t)layer * 3145728;
  const unsigned short* wbase = Wside + (size_t)(g * 1024 + n0 + u * 16 + l15) * 1024 + l4 * 8;
  bhalf8 wreg[32];
  #pragma unroll
  for (int kk = 0; kk < 32; ++kk) wreg[kk] = *(const bhalf8*)(wbase + kk * 32);

  // ---- bias regs (static epilogue mapping)
  const float* bi = bih + layer * 3072;
  const float* bh = bhh + layer * 3072;
  float bir[3][4], bhr[3][4];
  {
    int j0 = (tid & 7) << 2;
    #pragma unroll
    for (int q = 0; q < 4; ++q) {
      int n = n0 + j0 + q;
      #pragma unroll
      for (int gg = 0; gg < 3; ++gg) { bir[gg][q] = bi[gg * 1024 + n]; bhr[gg][q] = bh[gg * 1024 + n]; }
    }
  }
  float hcr[4] = {0.f, 0.f, 0.f, 0.f};   // fp32 zoneout carry

  int dead = 0;

  for (int s = 0; s < NSLOTS; ++s) {
    // anchor: asm "modifies" wreg -> compiler cannot rematerialize the loads
    #pragma unroll
    for (int i = 0; i < 32; ++i) asm volatile("" : "+v"(wreg[i]));

    const char* xsrc = (const char*)xb + (size_t)s * 131072;
    const bool actL0 = (layer == 0) && (s <= 499);
    const bool actL1 = (layer == 1) && (s >= 1 && s <= 500);

    // L0: pre-issue x chunks 0,1 (independent of flags) before the poll
    if (actL0 && w >= 8) {
      #pragma unroll
      for (int kcp = 0; kcp < 2; ++kcp) {
        #pragma unroll
        for (int i = 0; i < 2; ++i) {
          int idx = (w - 8) * 2 + i;
          int row = idx * 8 + (l >> 3);
          const char* ga = xsrc + row * 2048 + kcp * 128 + (((l & 7) * 16) ^ ((row & 7) << 4));
          GLL_PLAIN(ga, smem + 131072 + kcp * 8192 + idx * 1024);
        }
      }
      __builtin_amdgcn_sched_barrier(0);
    }

    // ---- store-only flag barrier: wave 0 polls lane-parallel
    if (s > 0) {
      if (w == 0 && !dead) {
        int it = 0;
        for (;;) {
          int f = cloadi(&flg[l]);                                   // flags 0..63
          int f2 = (l < 32) ? cloadi(&flg[64 + l]) : 0x7fffffff;     // flags 64..95
          int ok;
          if (layer == 0)  // L0(s) needs L0 done s-1; L1 done s-2 (h0 triple-buffered)
            ok = (f >= (l < 32 ? s : s - 1)) && (f2 >= s - 1);
          else             // L1(s) needs everyone done s-1
            ok = (f >= s) && (f2 >= s);
          if (__all(ok)) break;
          __builtin_amdgcn_s_sleep(2);
          if (++it > 2000000) { dead = 1; break; }   // bounded failsafe
        }
      }
      __builtin_amdgcn_s_barrier();
      __builtin_amdgcn_sched_barrier(0);
    }

    if (actL0) {
      // ---------------- layer 0: h0(s) = GRU(x(s), h0(s-1)) ----------------
      const char* h0src = h0b[(s + 2) % 3];        // h0(s-1)
      char* hout = h0b[s % 3];                     // h0(s)
      if (w < 8) {  // h0 plane: one burst, 16 instr/wave, single R
        #pragma unroll
        for (int i = 0; i < 16; ++i) {
          int idx = w + i * 8;
          int row = idx >> 1;
          int colb = (idx & 1) * 1024 + l * 16;
          GLL_COH(h0src + row * 2048 + (colb ^ ((row & 7) << 4)), smem + idx * 1024);
        }
      }
      asm volatile("s_waitcnt vmcnt(0)" ::: "memory");
      __builtin_amdgcn_s_barrier();
      __builtin_amdgcn_sched_barrier(0);

      floatx4 acc[4];
      #pragma unroll
      for (int m = 0; m < 4; ++m) acc[m] = (floatx4){0.f, 0.f, 0.f, 0.f};

      #pragma unroll
      for (int kc = 0; kc < 16; ++kc) {
        if (w >= 8 && kc + 2 < 16) {               // x ring: issue chunk kc+2 -> slot (kc+2)%3
          int kc2 = kc + 2;
          #pragma unroll
          for (int i = 0; i < 2; ++i) {
            int idx = (w - 8) * 2 + i;
            int row = idx * 8 + (l >> 3);
            const char* ga = xsrc + row * 2048 + kc2 * 128 + (((l & 7) * 16) ^ ((row & 7) << 4));
            GLL_PLAIN(ga, smem + 131072 + (kc2 % 3) * 8192 + idx * 1024);
          }
          __builtin_amdgcn_sched_barrier(0);
        }
        #pragma unroll
        for (int klL = 0; klL < 2; ++klL) {
          #pragma unroll
          for (int m = 0; m < 4; ++m) {
            int row = m * 16 + l15;
            const char* ap = (sd == 0)
              ? smem + 131072 + (kc % 3) * 8192 + row * 128 + ((klL * 64 + l4 * 16) ^ ((row & 7) << 4))
              : smem + row * 2048 + ((kc * 128 + klL * 64 + l4 * 16) ^ ((row & 7) << 4));
            bhalf8 a = *(const bhalf8*)ap;
            acc[m] = __builtin_amdgcn_mfma_f32_16x16x32_bf16(a, wreg[kc * 2 + klL], acc[m], 0, 0, 0);
          }
        }
        if (w >= 8) {
          if (kc <= 13)      asm volatile("s_waitcnt vmcnt(2)" ::: "memory");
          else if (kc == 14) asm volatile("s_waitcnt vmcnt(0)" ::: "memory");
        }
        __builtin_amdgcn_s_barrier();
        __builtin_amdgcn_sched_barrier(0);
      }
      __syncthreads();
      // Gs gate planes [6][64][34] f32 overlay
      float* Gsf = (float*)smem;
      int pl = (sd * 3 + g) * 2176;
      #pragma unroll
      for (int m = 0; m < 4; ++m)
        #pragma unroll
        for (int i = 0; i < 4; ++i)
          Gsf[pl + (m * 16 + l4 * 4 + i) * 34 + u * 16 + l15] = acc[m][i];
      __syncthreads();
      if (tid < 512) {
        int b = tid >> 3, j0 = (tid & 7) << 2;
        union { unsigned long long ull; unsigned short us[4]; } pk;
        #pragma unroll
        for (int q = 0; q < 4; ++q) {
          int j = j0 + q;
          float ir  = Gsf[0 * 2176 + b * 34 + j] + bir[0][q];
          float iz  = Gsf[1 * 2176 + b * 34 + j] + bir[1][q];
          float inn = Gsf[2 * 2176 + b * 34 + j] + bir[2][q];
          float hr  = Gsf[3 * 2176 + b * 34 + j] + bhr[0][q];
          float hz  = Gsf[4 * 2176 + b * 34 + j] + bhr[1][q];
          float hn  = Gsf[5 * 2176 + b * 34 + j] + bhr[2][q];
          float rg = 1.f / (1.f + expf(-(ir + hr)));
          float zg = 1.f / (1.f + expf(-(iz + hz)));
          float nc = tanhf(inn + rg * hn);
          float hp = hcr[q];
          float hnew = (1.f - zg) * nc + zg * hp;
          float hzo = 0.1f * hp + 0.9f * hnew;
          hcr[q] = hzo;
          pk.us[q] = f2b(hzo);
        }
        cstore((unsigned long long*)(hout + (size_t)b * 2048 + ((n0 + j0) << 1)), pk.ull);
      }
    } else if (actL1) {
      // -------- layer 1: h1(s-1) = GRU(h0(s-1), h1(s-2)); rows [half*32,+32) --------
      const char* h0src = h0b[(s + 2) % 3] + (size_t)half * 32 * 2048;
      const char* h1src = h1b[s & 1] + (size_t)half * 32 * 2048;
      char* hout = h1b[(s & 1) ^ 1];
      if (w < 8) {  // both planes in one burst: single R
        #pragma unroll
        for (int i = 0; i < 8; ++i) {
          int idx = w + i * 8;
          int row = idx >> 1;
          int colb = (idx & 1) * 1024 + l * 16;
          GLL_COH(h0src + row * 2048 + (colb ^ ((row & 7) << 4)), smem + idx * 1024);
        }
        #pragma unroll
        for (int i = 0; i < 8; ++i) {
          int idx = w + i * 8;
          int row = idx >> 1;
          int colb = (idx & 1) * 1024 + l * 16;
          GLL_COH(h1src + row * 2048 + (colb ^ ((row & 7) << 4)), smem + 65536 + idx * 1024);
        }
      }
      asm volatile("s_waitcnt vmcnt(0)" ::: "memory");
      __builtin_amdgcn_s_barrier();
      __builtin_amdgcn_sched_barrier(0);

      floatx4 acc[2];
      acc[0] = (floatx4){0.f, 0.f, 0.f, 0.f};
      acc[1] = (floatx4){0.f, 0.f, 0.f, 0.f};
      #pragma unroll
      for (int kc = 0; kc < 16; ++kc)
        #pragma unroll
        for (int klL = 0; klL < 2; ++klL)
          #pragma unroll
          for (int m = 0; m < 2; ++m) {
            int row = m * 16 + l15;
            const char* ap = smem + sd * 65536 + row * 2048 +
                             ((kc * 128 + klL * 64 + l4 * 16) ^ ((row & 7) << 4));
            bhalf8 a = *(const bhalf8*)ap;
            acc[m] = __builtin_amdgcn_mfma_f32_16x16x32_bf16(a, wreg[kc * 2 + klL], acc[m], 0, 0, 0);
          }

      // y(s-2) from the resident h1(s-2) plane — zero extra global loads
      if (c < 10 && w < 2 && s >= 2) {
        const unsigned short* woutrow = woutb + (size_t)(c * 16 + l15) * 1024 + l4 * 8;
        floatx4 accy = (floatx4){0.f, 0.f, 0.f, 0.f};
        #pragma unroll
        for (int kk = 0; kk < 32; ++kk) {
          int row = w * 16 + l15;
          const char* ap = smem + 65536 + row * 2048 + ((kk * 64 + l4 * 16) ^ ((row & 7) << 4));
          bhalf8 a = *(const bhalf8*)ap;
          bhalf8 bb = *(const bhalf8*)(woutrow + kk * 32);
          accy = __builtin_amdgcn_mfma_f32_16x16x32_bf16(a, bb, accy, 0, 0, 0);
        }
        int col = c * 16 + l15, t2 = s - 2;
        float bo = bout[col];
        #pragma unroll
        for (int i = 0; i < 4; ++i) {
          int brow = half * 32 + w * 16 + l4 * 4 + i;
          out[(size_t)brow * 80000 + (size_t)(col >> 1) * 1000 + t2 * 2 + (col & 1)] = accy[i] + bo;
        }
      }
      __syncthreads();
      // Gs planes [6][32][34] f32 overlay (on h0 plane region)
      float* Gsf = (float*)smem;
      int pl = (sd * 3 + g) * 1088;
      #pragma unroll
      for (int m = 0; m < 2; ++m)
        #pragma unroll
        for (int i = 0; i < 4; ++i)
          Gsf[pl + (m * 16 + l4 * 4 + i) * 34 + u * 16 + l15] = acc[m][i];
      __syncthreads();
      if (tid < 256) {
        int lr = tid >> 3, j0 = (tid & 7) << 2;
        union { unsigned long long ull; unsigned short us[4]; } pk;
        #pragma unroll
        for (int q = 0; q < 4; ++q) {
          int j = j0 + q;
          float ir  = Gsf[0 * 1088 + lr * 34 + j] + bir[0][q];
          float iz  = Gsf[1 * 1088 + lr * 34 + j] + bir[1][q];
          float inn = Gsf[2 * 1088 + lr * 34 + j] + bir[2][q];
          float hr  = Gsf[3 * 1088 + lr * 34 + j] + bhr[0][q];
          float hz  = Gsf[4 * 1088 + lr * 34 + j] + bhr[1][q];
          float hn  = Gsf[5 * 1088 + lr * 34 + j] + bhr[2][q];
          float rg = 1.f / (1.f + expf(-(ir + hr)));
          float zg = 1.f / (1.f + expf(-(iz + hz)));
          float nc = tanhf(inn + rg * hn);
          float hp = hcr[q];
          float hnew = (1.f - zg) * nc + zg * hp;
          float hzo = 0.1f * hp + 0.9f * hnew;
          hcr[q] = hzo;
          pk.us[q] = f2b(hzo);
        }
        cstore((unsigned long long*)(hout + (size_t)(half * 32 + lr) * 2048 + ((n0 + j0) << 1)), pk.ull);
      }
    } else if (layer == 1 && s == 501) {
      // final y(499): gather h1(499) plane only, then y
      const char* h1src = h1b[s & 1] + (size_t)half * 32 * 2048;
      if (w < 8) {
        #pragma unroll
        for (int i = 0; i < 8; ++i) {
          int idx = w + i * 8;
          int row = idx >> 1;
          int colb = (idx & 1) * 1024 + l * 16;
          GLL_COH(h1src + row * 2048 + (colb ^ ((row & 7) << 4)), smem + 65536 + idx * 1024);
        }
      }
      asm volatile("s_waitcnt vmcnt(0)" ::: "memory");
      __builtin_amdgcn_s_barrier();
      __builtin_amdgcn_sched_barrier(0);
      if (c < 10 && w < 2) {
        const unsigned short* woutrow = woutb + (size_t)(c * 16 + l15) * 1024 + l4 * 8;
        floatx4 accy = (floatx4){0.f, 0.f, 0.f, 0.f};
        #pragma unroll
        for (int kk = 0; kk < 32; ++kk) {
          int row = w * 16 + l15;
          const char* ap = smem + 65536 + row * 2048 + ((kk * 64 + l4 * 16) ^ ((row & 7) << 4));
          bhalf8 a = *(const bhalf8*)ap;
          bhalf8 bb = *(const bhalf8*)(woutrow + kk * 32);
          accy = __builtin_amdgcn_mfma_f32_16x16x32_bf16(a, bb, accy, 0, 0, 0);
        }
        int col = c * 16 + l15, t2 = s - 2;
        float bo = bout[col];
        #pragma unroll
        for (int i = 0; i < 4; ++i) {
          int brow = half * 32 + w * 16 + l4 * 4 + i;
          out[(size_t)brow * 80000 + (size_t)(col >> 1) * 1000 + t2 * 2 + (col & 1)] = accy[i] + bo;
        }
      }
    }

    // completion flag: syncthreads drains this WG's coherent stores (per-wave vmcnt 0)
    __syncthreads();
    if (tid == 0)
      __hip_atomic_store(&flg[wg], s + 1, __ATOMIC_RELAXED, __HIP_MEMORY_SCOPE_AGENT);
  }
}

extern "C" void kernel_launch(void* const* d_in, const int* in_sizes, int n_in,
                              void* d_out, int out_size, void* d_ws, size_t ws_size,
                              hipStream_t stream) {
  const float* res  = (const float*)d_in[0];
  const float* Wih  = (const float*)d_in[1];
  const float* Whh  = (const float*)d_in[2];
  const float* bih  = (const float*)d_in[3];
  const float* bhh  = (const float*)d_in[4];
  const float* Wout = (const float*)d_in[5];
  const float* bout = (const float*)d_in[6];
  float* out = (float*)d_out;
  char* ws = (char*)d_ws;
  if (ws_size < 91685888u) return;  // workspace too small; fail loudly via wrong output

  unsigned short* woutb = (unsigned short*)(ws + 656384);
  unsigned short* wihb  = (unsigned short*)(ws + 984064);
  unsigned short* whhb  = (unsigned short*)(ws + 13566976);
  unsigned short* xb    = (unsigned short*)(ws + 26149888);

  // zero flags + h state (h0 x3, h1 x2)
  hipMemsetAsync(ws, 0, 656384, stream);
  prep_w<<<4096, 256, 0, stream>>>(Wih, Whh, Wout, wihb, whhb, woutb);
  prep_x<<<dim3(16, 32, 64), dim3(32, 8), 0, stream>>>(res, xb);
  gru_main<<<NWG, BLOCK, 0, stream>>>(xb, wihb, whhb, woutb, bih, bhh, bout, ws, out);
}